// Round 4
// baseline (473.860 us; speedup 1.0000x reference)
//
#include <hip/hip_runtime.h>
#include <hip/hip_cooperative_groups.h>
#include <math.h>

namespace cg = cooperative_groups;

#define NPTS 8192
#define NB 4
#define BLK 256
#define NSEG 8              // segments per (b,dir): 8 * 16 xchunks * 8 bd = 1024 blocks
#define XCHUNKS 16          // 8192 q / (BLK * Q)
#define Q 2
#define NGROUPS 4096        // ref pairs per (arr,b)
#define TOTAL_BLOCKS (XCHUNKS * NSEG * 2 * NB)   // 1024 = 4 blocks/CU (coop-resident)

typedef __attribute__((ext_vector_type(2))) float v2f;
typedef __attribute__((ext_vector_type(4))) float v4f;

// v_pk_fma_f32 (NOTE: measured half-rate ~4cyc on gfx950; win is issue slots, not flops)
// D.lo = S0.lo*S1.lo + S2.lo ; D.hi = S0.hi*S1.lo + S2.hi   (broadcast S1.lo)
__device__ __forceinline__ v2f pk_fma_s1lo(v2f a, v2f q, v2f c) {
    v2f d;
    asm("v_pk_fma_f32 %0, %1, %2, %3 op_sel:[0,0,0] op_sel_hi:[1,0,1]"
        : "=v"(d) : "v"(a), "v"(q), "v"(c));
    return d;
}
// D.lo = S0.lo*S1.hi + S2.lo ; D.hi = S0.hi*S1.hi + S2.hi   (broadcast S1.hi)
__device__ __forceinline__ v2f pk_fma_s1hi(v2f a, v2f q, v2f c) {
    v2f d;
    asm("v_pk_fma_f32 %0, %1, %2, %3 op_sel:[0,1,0] op_sel_hi:[1,1,1]"
        : "=v"(d) : "v"(a), "v"(q), "v"(c));
    return d;
}
__device__ __forceinline__ float min3f(float a, float b, float c) {
    float d;
    asm("v_min3_f32 %0, %1, %2, %3" : "=v"(d) : "v"(a), "v"(b), "v"(c));
    return d;
}

// monotone float -> uint map (for exact atomicMin on f32, incl. negatives)
__device__ __forceinline__ unsigned enc_f32(float f) {
    unsigned b = __float_as_uint(f);
    return (b & 0x80000000u) ? ~b : (b | 0x80000000u);
}
__device__ __forceinline__ float dec_f32(unsigned u) {
    unsigned b = (u & 0x80000000u) ? (u ^ 0x80000000u) : ~u;
    return __uint_as_float(b);
}

// Single cooperative kernel:
//  P0: init encoded-min array; pack refs as per-pair SoA {x,x,y,y | z,z,w,w}
//  P1: per (bd,seg,xchunk) block: stream refs through L1 (uniform loads, no LDS,
//      no barriers), 2 queries/thread, min via packed fma + min3; atomicMin combine
//  P2: decode, sqrt, per-block sums   P3: final 256-entry tree -> out
__global__ __launch_bounds__(BLK, 4) void chamfer_fused(
    const float* __restrict__ tmpl, const float* __restrict__ src,
    float* __restrict__ out, float* __restrict__ ws)
{
    v4f* packed      = (v4f*)ws;                        // 1 MB: 8*4096 groups * 32 B
    unsigned* pmin   = (unsigned*)(ws + (1 << 18));     // 256 KB: 8*8192 u32
    float* bsums     = (float*)(pmin + 2 * NB * NPTS);  // 1 KB: 256 floats
    const int tid  = threadIdx.x;
    const int gtid = blockIdx.x * BLK + tid;
    cg::grid_group grid = cg::this_grid();
    __shared__ float wsum[BLK / 64];

    // ---------------- P0 ----------------
    if (gtid < 2 * NB * NPTS) pmin[gtid] = 0xFFFFFFFFu;
    if (gtid < 2 * NB * NGROUPS) {
        const int g    = gtid;            // global group id
        const int arrb = g >> 12;         // /4096 : 0..7 = arr*4 + b
        const int lg   = g & 4095;
        const int arr  = arrb >> 2, b = arrb & 3;
        const float* in = (arr ? src : tmpl) + ((size_t)b * NPTS + 2 * lg) * 3;
        const float xA = in[0], yA = in[1], zA = in[2];
        const float xB = in[3], yB = in[4], zB = in[5];
        const float wA = fmaf(xA, xA, fmaf(yA, yA, zA * zA));
        const float wB = fmaf(xB, xB, fmaf(yB, yB, zB * zB));
        packed[2 * g]     = (v4f){xA, xB, yA, yB};
        packed[2 * g + 1] = (v4f){zA, zB, wA, wB};
    }
    grid.sync();

    // ---------------- P1 ----------------
    {
        const int bid = blockIdx.x;
        const int bd  = bid >> 7;          // 0..7
        const int seg = (bid >> 4) & 7;    // 0..7
        const int xc  = bid & 15;          // 0..15
        const int b = bd >> 1, dir = bd & 1;
        const float* qp = (dir ? src : tmpl) + (size_t)b * NPTS * 3;
        // refs are the OTHER array: arrsel = dir ^ 1
        const v4f* rbase = packed +
            (((size_t)((dir ^ 1) * 4 + b) * NGROUPS + (size_t)seg * 512) * 2);

        const int q0 = xc * (BLK * Q) + tid;
        const int q1 = q0 + BLK;
        const float qx0 = qp[3 * q0], qy0 = qp[3 * q0 + 1], qz0 = qp[3 * q0 + 2];
        const float qx1 = qp[3 * q1], qy1 = qp[3 * q1 + 1], qz1 = qp[3 * q1 + 2];
        // fold -2 into queries (exact pow2 scale)
        const v2f qxy0 = (v2f){-2.f * qx0, -2.f * qy0};
        const v2f qxy1 = (v2f){-2.f * qx1, -2.f * qy1};
        const v2f qzz  = (v2f){-2.f * qz0, -2.f * qz1};
        float mn0 = 3.4e38f, mn1 = 3.4e38f;

#pragma unroll 4
        for (int j = 0; j < 512; j++) {
            const v4f A = rbase[2 * j];      // (xA,xB,yA,yB) uniform -> L1 broadcast
            const v4f B = rbase[2 * j + 1];  // (zA,zB,wA,wB)
            const v2f ax = A.lo, ay = A.hi, az = B.lo, aw = B.hi;
            v2f t0 = pk_fma_s1lo(ax, qxy0, aw);   // x*qx0 + w
            t0     = pk_fma_s1hi(ay, qxy0, t0);   // + y*qy0
            t0     = pk_fma_s1lo(az, qzz,  t0);   // + z*qz0
            v2f t1 = pk_fma_s1lo(ax, qxy1, aw);
            t1     = pk_fma_s1hi(ay, qxy1, t1);
            t1     = pk_fma_s1hi(az, qzz,  t1);   // qz1 = qzz.hi
            mn0 = min3f(mn0, t0.x, t0.y);
            mn1 = min3f(mn1, t1.x, t1.y);
        }
        atomicMin(&pmin[bd * NPTS + q0], enc_f32(mn0));
        atomicMin(&pmin[bd * NPTS + q1], enc_f32(mn1));
    }
    grid.sync();

    // ---------------- P2 ----------------
    if (blockIdx.x < 256) {
        const int t  = blockIdx.x * BLK + tid;     // 0 .. 65535
        const int bd = t >> 13;
        const int qi = t & (NPTS - 1);
        const int b = bd >> 1, dir = bd & 1;
        const float* qp = (dir ? src : tmpl) + (size_t)b * NPTS * 3;
        const float qx = qp[3 * qi], qy = qp[3 * qi + 1], qz = qp[3 * qi + 2];
        const float sq = qx * qx + qy * qy + qz * qz;
        const float m  = dec_f32(pmin[t]);
        float v = sqrtf(fmaxf(sq + m, 0.f));
#pragma unroll
        for (int off = 32; off > 0; off >>= 1) v += __shfl_down(v, off, 64);
        if ((tid & 63) == 0) wsum[tid >> 6] = v;
        __syncthreads();
        if (tid == 0) {
            float s = 0.f;
#pragma unroll
            for (int w = 0; w < BLK / 64; w++) s += wsum[w];
            bsums[blockIdx.x] = s;
        }
    }
    grid.sync();

    // ---------------- P3 ----------------
    if (blockIdx.x == 0) {
        float v = bsums[tid];   // tid < 256, bsums has 256 entries
#pragma unroll
        for (int off = 32; off > 0; off >>= 1) v += __shfl_down(v, off, 64);
        if ((tid & 63) == 0) wsum[tid >> 6] = v;
        __syncthreads();
        if (tid == 0) {
            float s = 0.f;
#pragma unroll
            for (int w = 0; w < BLK / 64; w++) s += wsum[w];
            // mean over 8192 q * 2 dirs (avg) * 4 batches (mean) = /65536
            out[0] = s * (1.0f / 65536.0f);
        }
    }
}

extern "C" void kernel_launch(void* const* d_in, const int* in_sizes, int n_in,
                              void* d_out, int out_size, void* d_ws, size_t ws_size,
                              hipStream_t stream) {
    const float* tmpl = (const float*)d_in[0];
    const float* src  = (const float*)d_in[1];
    float* out = (float*)d_out;
    float* ws  = (float*)d_ws;   // needs 1.25 MB (packed 1MB + pmin 256KB + bsums 1KB)

    void* args[] = { (void*)&tmpl, (void*)&src, (void*)&out, (void*)&ws };
    hipLaunchCooperativeKernel((void*)chamfer_fused, dim3(TOTAL_BLOCKS), dim3(BLK),
                               (void**)args, 0, stream);
}

// Round 5
// 103.176 us; speedup vs baseline: 4.5927x; 4.5927x over previous
//
#include <hip/hip_runtime.h>
#include <math.h>

#define NPTS 8192
#define NB 4
#define BLK 256
#define Q 8            // queries per thread (4 packed pairs)
#define TILE 256       // refs staged per block; == seg_len (compile-time!)
#define NSEG 32        // 8192/256; grid = 4 x 32 x 8 = 1024 blocks = 4/CU

typedef __attribute__((ext_vector_type(2))) float v2f;
typedef __attribute__((ext_vector_type(4))) float v4f;

// v_pk_fma_f32 with op_sel dword broadcasts.
// (measured r1->r2: half-rate ~4cyc on gfx950 -- win is issue slots, not flops)
// t = bcast_lo(a) * q + bcast_hi(c)    (x*q + w)
__device__ __forceinline__ v2f pk_fma_xw(v2f a, v2f q, v2f c) {
    v2f d;
    asm("v_pk_fma_f32 %0, %1, %2, %3 op_sel:[0,0,1] op_sel_hi:[0,1,1]"
        : "=v"(d) : "v"(a), "v"(q), "v"(c));
    return d;
}
// t = bcast_hi(a) * q + t
__device__ __forceinline__ v2f pk_fma_bhi(v2f a, v2f q, v2f c) {
    v2f d;
    asm("v_pk_fma_f32 %0, %1, %2, %3 op_sel:[1,0,0] op_sel_hi:[1,1,1]"
        : "=v"(d) : "v"(a), "v"(q), "v"(c));
    return d;
}
// t = bcast_lo(a) * q + t
__device__ __forceinline__ v2f pk_fma_blo(v2f a, v2f q, v2f c) {
    v2f d;
    asm("v_pk_fma_f32 %0, %1, %2, %3 op_sel:[0,0,0] op_sel_hi:[0,1,1]"
        : "=v"(d) : "v"(a), "v"(q), "v"(c));
    return d;
}
__device__ __forceinline__ float min3f(float a, float b, float c) {
    float d;
    asm("v_min3_f32 %0, %1, %2, %3" : "=v"(d) : "v"(a), "v"(b), "v"(c));
    return d;
}

// Kernel 1: partial[bd][seg][q] = min over seg refs of (|r|^2 - 2 q.r)
// (|q|^2 added in kernel 2; min commutes with +|q|^2 and the clamp.)
// Refs staged in LDS as (rx,ry,rz,|r|^2); -2 folded into queries (exact pow2).
__global__ __launch_bounds__(BLK) void chamfer_partial(
    const float* __restrict__ tmpl, const float* __restrict__ src,
    float* __restrict__ partial)
{
    __shared__ v4f lds[TILE + 2];       // +2: prefetch overreach pad
    const int bd  = blockIdx.z;          // 0..7 = b*2 + dir
    const int b   = bd >> 1;
    const int dir = bd & 1;
    const float* qp = (dir ? src : tmpl) + (size_t)b * NPTS * 3;
    const float* rp = (dir ? tmpl : src) + (size_t)b * NPTS * 3;
    const int tid   = threadIdx.x;
    const int qbase = blockIdx.x * (BLK * Q);

    // stage this block's TILE refs (one per thread; TILE == BLK)
    {
        const int ri = blockIdx.y * TILE + tid;
        const float rx = rp[3 * ri + 0];
        const float ry = rp[3 * ri + 1];
        const float rz = rp[3 * ri + 2];
        const float w  = fmaf(rx, rx, fmaf(ry, ry, rz * rz));
        lds[tid] = (v4f){rx, ry, rz, w};
    }

    v2f qx[Q / 2], qy[Q / 2], qz[Q / 2];
    float mn[Q];
#pragma unroll
    for (int p = 0; p < Q / 2; p++) {
        const int qi0 = qbase + (2 * p) * BLK + tid;
        const int qi1 = qbase + (2 * p + 1) * BLK + tid;
        qx[p] = (v2f){-2.f * qp[3 * qi0 + 0], -2.f * qp[3 * qi1 + 0]};
        qy[p] = (v2f){-2.f * qp[3 * qi0 + 1], -2.f * qp[3 * qi1 + 1]};
        qz[p] = (v2f){-2.f * qp[3 * qi0 + 2], -2.f * qp[3 * qi1 + 2]};
        mn[2 * p]     = 3.4e38f;
        mn[2 * p + 1] = 3.4e38f;
    }
    __syncthreads();

    // inner loop: 2 refs/iter, explicit next-pair register prefetch so the
    // ds_read -> pk_fma distance is a full iteration body (~112 VALU cyc)
    v4f A = lds[0], B = lds[1];
#pragma unroll 4
    for (int j = 0; j < TILE; j += 2) {
        const v4f A2 = lds[j + 2];
        const v4f B2 = lds[j + 3];
        const v2f Axy = A.lo, Azw = A.hi;
        const v2f Bxy = B.lo, Bzw = B.hi;
#pragma unroll
        for (int p = 0; p < Q / 2; p++) {
            v2f ta = pk_fma_xw (Axy, qx[p], Azw);  // x*qx + w
            ta     = pk_fma_bhi(Axy, qy[p], ta);   // + y*qy
            ta     = pk_fma_blo(Azw, qz[p], ta);   // + z*qz
            v2f tb = pk_fma_xw (Bxy, qx[p], Bzw);
            tb     = pk_fma_bhi(Bxy, qy[p], tb);
            tb     = pk_fma_blo(Bzw, qz[p], tb);
            mn[2 * p]     = min3f(mn[2 * p],     ta.x, tb.x);
            mn[2 * p + 1] = min3f(mn[2 * p + 1], ta.y, tb.y);
        }
        A = A2; B = B2;
    }

    const size_t base = ((size_t)bd * NSEG + blockIdx.y) * NPTS;
#pragma unroll
    for (int k = 0; k < Q; k++)
        partial[base + qbase + k * BLK + tid] = mn[k];
}

// Kernel 2: combine segment partials, add |q|^2, clamp, sqrt, global mean.
__global__ __launch_bounds__(BLK) void chamfer_reduce(
    const float* __restrict__ tmpl, const float* __restrict__ src,
    const float* __restrict__ partial, float* __restrict__ out)
{
    const int t  = blockIdx.x * BLK + threadIdx.x;  // 0 .. 8*NPTS-1
    const int bd = t >> 13;                         // / NPTS
    const int qi = t & (NPTS - 1);
    const int b  = bd >> 1;
    const int dir = bd & 1;
    const float* qp = (dir ? src : tmpl) + (size_t)b * NPTS * 3;
    const float qx = qp[3 * qi + 0];
    const float qy = qp[3 * qi + 1];
    const float qz = qp[3 * qi + 2];
    const float sq = qx * qx + qy * qy + qz * qz;

    float m = 3.4e38f;
#pragma unroll 4
    for (int s = 0; s < NSEG; s++)
        m = fminf(m, partial[((size_t)bd * NSEG + s) * NPTS + qi]);

    float v = sqrtf(fmaxf(sq + m, 0.f));

    // wave reduction (64 lanes)
#pragma unroll
    for (int off = 32; off > 0; off >>= 1)
        v += __shfl_down(v, off, 64);

    __shared__ float wsum[BLK / 64];
    const int lane = threadIdx.x & 63;
    const int wid  = threadIdx.x >> 6;
    if (lane == 0) wsum[wid] = v;
    __syncthreads();
    if (threadIdx.x == 0) {
        float s = 0.f;
#pragma unroll
        for (int w = 0; w < BLK / 64; w++) s += wsum[w];
        // mean over N (8192) * avg 2 dirs * mean 4 batches = /65536
        atomicAdd(out, s * (1.0f / 65536.0f));
    }
}

extern "C" void kernel_launch(void* const* d_in, const int* in_sizes, int n_in,
                              void* d_out, int out_size, void* d_ws, size_t ws_size,
                              hipStream_t stream) {
    const float* tmpl = (const float*)d_in[0];
    const float* src  = (const float*)d_in[1];
    float* out      = (float*)d_out;
    float* partial  = (float*)d_ws;   // needs 8*NSEG*NPTS*4 = 8 MB

    hipMemsetAsync(d_out, 0, sizeof(float), stream);

    dim3 g1(NPTS / (BLK * Q), NSEG, 2 * NB);
    chamfer_partial<<<g1, BLK, 0, stream>>>(tmpl, src, partial);

    chamfer_reduce<<<(2 * NB * NPTS) / BLK, BLK, 0, stream>>>(tmpl, src, partial, out);
}

// Round 6
// 93.029 us; speedup vs baseline: 5.0937x; 1.1091x over previous
//
#include <hip/hip_runtime.h>
#include <math.h>

#define NPTS 8192
#define NB 4
#define BLK 256

typedef __attribute__((ext_vector_type(8))) short  short8v;  // 4 VGPRs = 8 bf16
typedef __attribute__((ext_vector_type(16))) float f32x16;   // MFMA 32x32 acc

__device__ __forceinline__ float min3f(float a, float b, float c) {
    float d;
    asm("v_min3_f32 %0, %1, %2, %3" : "=v"(d) : "v"(a), "v"(b), "v"(c));
    return d;
}
// RNE float->bf16 (no NaN inputs here)
__device__ __forceinline__ unsigned short f2bf(float f) {
    unsigned u = __float_as_uint(f);
    return (unsigned short)((u + 0x7FFFu + ((u >> 16) & 1u)) >> 16);
}
__device__ __forceinline__ float bf2f(unsigned short h) {
    return __uint_as_float(((unsigned)h) << 16);
}

// ---------------------------------------------------------------------------
// P0: pack both arrays into MFMA fragment order.
// K-slot pairing (A = refs, B = queries, m = -2q):
//  k0-2: rh_c * mh_c | k3-5: rl_c * mh_c | k6-8: rh_c * ml_c
//  k9:   w_h  * 1    | k10:  w_l  * 1    | k11-15: 0
// acc = (-2 q . r) + |r|^2  (+O(1e-6): dropped rl*ml and split residuals)
// Fragment order per 32-point tile: lane l holds point (tile*32 + (l&31)),
// k-slots 8*(l>>5)..+7, stored as contiguous 16B -> tile = 1024 B.
// ---------------------------------------------------------------------------
__global__ __launch_bounds__(BLK) void chamfer_pack(
    const float* __restrict__ tmpl, const float* __restrict__ src,
    short* __restrict__ apack, short* __restrict__ bpack)
{
    const int t   = blockIdx.x * BLK + threadIdx.x;   // 0..65535
    const int arr = t >> 15;
    const int b   = (t >> 13) & 3;
    const int i   = t & (NPTS - 1);
    const float* p = (arr ? src : tmpl) + ((size_t)b * NPTS + i) * 3;
    const float x = p[0], y = p[1], z = p[2];

    // ref-side splits
    const unsigned short xh = f2bf(x), yh = f2bf(y), zh = f2bf(z);
    const unsigned short xl = f2bf(x - bf2f(xh));
    const unsigned short yl = f2bf(y - bf2f(yh));
    const unsigned short zl = f2bf(z - bf2f(zh));
    const float w = fmaf(x, x, fmaf(y, y, z * z));
    const unsigned short wh = f2bf(w);
    const unsigned short wl = f2bf(w - bf2f(wh));
    // query-side splits of m = -2q (exact pow2 scale in fp32)
    const float mx = -2.f * x, my = -2.f * y, mz = -2.f * z;
    const unsigned short mxh = f2bf(mx), myh = f2bf(my), mzh = f2bf(mz);
    const unsigned short mxl = f2bf(mx - bf2f(mxh));
    const unsigned short myl = f2bf(my - bf2f(myh));
    const unsigned short mzl = f2bf(mz - bf2f(mzh));
    const unsigned short ONE = 0x3F80;  // bf16 1.0

    const size_t base = (size_t)(arr * 4 + b) * (NPTS * 16);  // shorts
    const int    tl   = i >> 5, lr = i & 31;
    short* ap = apack + base + (size_t)tl * 512;
    short* bp = bpack + base + (size_t)tl * 512;

    const short8v a0 = {(short)xh, (short)yh, (short)zh, (short)xl,
                        (short)yl, (short)zl, (short)xh, (short)yh};
    const short8v a1 = {(short)zh, (short)wh, (short)wl, 0, 0, 0, 0, 0};
    *(short8v*)(ap + lr * 8)        = a0;
    *(short8v*)(ap + (lr + 32) * 8) = a1;

    const short8v b0 = {(short)mxh, (short)myh, (short)mzh, (short)mxh,
                        (short)myh, (short)mzh, (short)mxl, (short)myl};
    const short8v b1 = {(short)mzl, (short)ONE, (short)ONE, 0, 0, 0, 0, 0};
    *(short8v*)(bp + lr * 8)        = b0;
    *(short8v*)(bp + (lr + 32) * 8) = b1;
}

// ---------------------------------------------------------------------------
// P1: per (bd, seg): each wave owns 32 queries (B frag fixed in regs),
// streams 4096 refs (128 tiles) through double-buffered LDS; per tile:
// 1 ds_read_b128 + 1 MFMA + 8 min3. Min over rows is in-lane (row mapping
// irrelevant); finish with shfl_xor(32). C col = lane&31 (HW-verified).
// ---------------------------------------------------------------------------
__global__ __launch_bounds__(BLK) void chamfer_mfma(
    const short* __restrict__ apack, const short* __restrict__ bpack,
    float* __restrict__ partial)
{
    __shared__ __align__(16) short lds[2][8192];   // 2 x 16 KB (16 tiles each)
    const int bd  = blockIdx.z;     // 0..7
    const int seg = blockIdx.y;     // 0..1
    const int qb  = blockIdx.x;     // 0..63
    const int b = bd >> 1, dir = bd & 1;
    const short* ab = apack + (size_t)((dir ^ 1) * 4 + b) * (NPTS * 16)
                            + (size_t)seg * 128 * 512;    // seg's 128 tiles
    const short* bb = bpack + (size_t)(dir * 4 + b) * (NPTS * 16);
    const int tid = threadIdx.x, wid = tid >> 6, lane = tid & 63;

    const int qt = qb * 4 + wid;                          // query tile 0..255
    const short8v bfrag = *(const short8v*)(bb + (size_t)qt * 512 + lane * 8);

    float mn = 3.4e38f;
    short8v st[4];
#define LOADREGS(c) { const short* s_ = ab + (size_t)(c) * 8192;               \
    _Pragma("unroll") for (int i_ = 0; i_ < 4; i_++)                           \
        st[i_] = *(const short8v*)(s_ + i_ * 2048 + tid * 8); }
#define WRITEBUF(bf) { _Pragma("unroll") for (int i_ = 0; i_ < 4; i_++)        \
        *(short8v*)(&lds[bf][i_ * 2048 + tid * 8]) = st[i_]; }

    LOADREGS(0); WRITEBUF(0); LOADREGS(1);
    __syncthreads();
    for (int c = 0; c < 8; c++) {
        if (c + 1 < 8) WRITEBUF((c + 1) & 1);
        if (c + 2 < 8) LOADREGS(c + 2);
        const short* lbase = &lds[c & 1][lane * 8];
#pragma unroll
        for (int t = 0; t < 16; t++) {
            const short8v a = *(const short8v*)(lbase + t * 512);
            f32x16 d = __builtin_amdgcn_mfma_f32_32x32x16_bf16(
                a, bfrag, (f32x16)(0.f), 0, 0, 0);
            const float g0 = min3f(d[0],  d[1],  d[2]);
            const float g1 = min3f(d[3],  d[4],  d[5]);
            const float g2 = min3f(d[6],  d[7],  d[8]);
            const float g3 = min3f(d[9],  d[10], d[11]);
            const float g4 = min3f(d[12], d[13], d[14]);
            mn = min3f(mn, g0, g1);
            mn = min3f(mn, g2, g3);
            mn = min3f(mn, g4, d[15]);
        }
        __syncthreads();
    }
    mn = fminf(mn, __shfl_xor(mn, 32, 64));
    if (lane < 32)
        partial[((size_t)bd * 2 + seg) * NPTS + qt * 32 + lane] = mn;
}

// ---------------------------------------------------------------------------
// P2: combine 2 segment mins, add |q|^2 (exact fp32), clamp, sqrt, mean.
// ---------------------------------------------------------------------------
__global__ __launch_bounds__(BLK) void chamfer_reduce(
    const float* __restrict__ tmpl, const float* __restrict__ src,
    const float* __restrict__ partial, float* __restrict__ out)
{
    const int t  = blockIdx.x * BLK + threadIdx.x;  // 0 .. 8*NPTS-1
    const int bd = t >> 13;
    const int qi = t & (NPTS - 1);
    const int b  = bd >> 1;
    const int dir = bd & 1;
    const float* qp = (dir ? src : tmpl) + (size_t)b * NPTS * 3;
    const float qx = qp[3 * qi + 0];
    const float qy = qp[3 * qi + 1];
    const float qz = qp[3 * qi + 2];
    const float sq = qx * qx + qy * qy + qz * qz;

    const float m = fminf(partial[((size_t)bd * 2 + 0) * NPTS + qi],
                          partial[((size_t)bd * 2 + 1) * NPTS + qi]);
    float v = sqrtf(fmaxf(sq + m, 0.f));

#pragma unroll
    for (int off = 32; off > 0; off >>= 1)
        v += __shfl_down(v, off, 64);

    __shared__ float wsum[BLK / 64];
    const int lane = threadIdx.x & 63;
    const int wid  = threadIdx.x >> 6;
    if (lane == 0) wsum[wid] = v;
    __syncthreads();
    if (threadIdx.x == 0) {
        float s = 0.f;
#pragma unroll
        for (int w = 0; w < BLK / 64; w++) s += wsum[w];
        atomicAdd(out, s * (1.0f / 65536.0f));
    }
}

extern "C" void kernel_launch(void* const* d_in, const int* in_sizes, int n_in,
                              void* d_out, int out_size, void* d_ws, size_t ws_size,
                              hipStream_t stream) {
    const float* tmpl = (const float*)d_in[0];
    const float* src  = (const float*)d_in[1];
    float* out = (float*)d_out;

    // ws layout: apack 2 MB | bpack 2 MB | partial 512 KB  (needs 4.5 MB)
    short* apack   = (short*)d_ws;
    short* bpack   = apack + (size_t)8 * NPTS * 16;
    float* partial = (float*)(bpack + (size_t)8 * NPTS * 16);

    hipMemsetAsync(d_out, 0, sizeof(float), stream);

    chamfer_pack<<<(2 * NB * NPTS) / BLK, BLK, 0, stream>>>(tmpl, src, apack, bpack);

    dim3 g1(NPTS / 128, 2, 2 * NB);   // 64 x 2 x 8 = 1024 blocks
    chamfer_mfma<<<g1, BLK, 0, stream>>>(apack, bpack, partial);

    chamfer_reduce<<<(2 * NB * NPTS) / BLK, BLK, 0, stream>>>(tmpl, src, partial, out);
}

// Round 7
// 89.433 us; speedup vs baseline: 5.2985x; 1.0402x over previous
//
#include <hip/hip_runtime.h>
#include <math.h>

#define NPTS 8192
#define NB 4
#define BLK 256
#define MSEG 4          // ref segments per (b,dir); seg = 64 tiles = 2048 refs

typedef __attribute__((ext_vector_type(8))) short  short8v;  // 4 VGPRs = 8 bf16
typedef __attribute__((ext_vector_type(16))) float f32x16;   // MFMA 32x32 acc

__device__ __forceinline__ float min3f(float a, float b, float c) {
    float d;
    asm("v_min3_f32 %0, %1, %2, %3" : "=v"(d) : "v"(a), "v"(b), "v"(c));
    return d;
}
// RNE float->bf16 (no NaN inputs here)
__device__ __forceinline__ unsigned short f2bf(float f) {
    unsigned u = __float_as_uint(f);
    return (unsigned short)((u + 0x7FFFu + ((u >> 16) & 1u)) >> 16);
}
__device__ __forceinline__ float bf2f(unsigned short h) {
    return __uint_as_float(((unsigned)h) << 16);
}

// ---------------------------------------------------------------------------
// P0: pack both arrays into MFMA fragment order (identical math to r6 —
// harness-verified absmax 0.0).
// K-slot pairing (A = refs, B = queries, m = -2q):
//  k0-2: rh_c * mh_c | k3-5: rl_c * mh_c | k6-8: rh_c * ml_c
//  k9:   w_h  * 1    | k10:  w_l  * 1    | k11-15: 0
// acc = (-2 q . r) + |r|^2. Lane l holds point (tile*32 + (l&31)),
// k-slots 8*(l>>5)..+7 as one contiguous short8v -> tile = 1024 B.
// Also zeroes out[0] (replaces the memset graph node; stream-ordered
// ahead of chamfer_reduce's atomicAdd).
// ---------------------------------------------------------------------------
__global__ __launch_bounds__(BLK) void chamfer_pack(
    const float* __restrict__ tmpl, const float* __restrict__ src,
    short* __restrict__ apack, short* __restrict__ bpack,
    float* __restrict__ out)
{
    if (blockIdx.x == 0 && threadIdx.x == 0) out[0] = 0.f;

    const int t   = blockIdx.x * BLK + threadIdx.x;   // 0..65535
    const int arr = t >> 15;
    const int b   = (t >> 13) & 3;
    const int i   = t & (NPTS - 1);
    const float* p = (arr ? src : tmpl) + ((size_t)b * NPTS + i) * 3;
    const float x = p[0], y = p[1], z = p[2];

    // ref-side splits
    const unsigned short xh = f2bf(x), yh = f2bf(y), zh = f2bf(z);
    const unsigned short xl = f2bf(x - bf2f(xh));
    const unsigned short yl = f2bf(y - bf2f(yh));
    const unsigned short zl = f2bf(z - bf2f(zh));
    const float w = fmaf(x, x, fmaf(y, y, z * z));
    const unsigned short wh = f2bf(w);
    const unsigned short wl = f2bf(w - bf2f(wh));
    // query-side splits of m = -2q (exact pow2 scale in fp32)
    const float mx = -2.f * x, my = -2.f * y, mz = -2.f * z;
    const unsigned short mxh = f2bf(mx), myh = f2bf(my), mzh = f2bf(mz);
    const unsigned short mxl = f2bf(mx - bf2f(mxh));
    const unsigned short myl = f2bf(my - bf2f(myh));
    const unsigned short mzl = f2bf(mz - bf2f(mzh));
    const unsigned short ONE = 0x3F80;  // bf16 1.0

    const size_t base = (size_t)(arr * 4 + b) * (NPTS * 16);  // shorts
    const int    tl   = i >> 5, lr = i & 31;
    short* ap = apack + base + (size_t)tl * 512;
    short* bp = bpack + base + (size_t)tl * 512;

    const short8v a0 = {(short)xh, (short)yh, (short)zh, (short)xl,
                        (short)yl, (short)zl, (short)xh, (short)yh};
    const short8v a1 = {(short)zh, (short)wh, (short)wl, 0, 0, 0, 0, 0};
    *(short8v*)(ap + lr * 8)        = a0;
    *(short8v*)(ap + (lr + 32) * 8) = a1;

    const short8v b0 = {(short)mxh, (short)myh, (short)mzh, (short)mxh,
                        (short)myh, (short)mzh, (short)mxl, (short)myl};
    const short8v b1 = {(short)mzl, (short)ONE, (short)ONE, 0, 0, 0, 0, 0};
    *(short8v*)(bp + lr * 8)        = b0;
    *(short8v*)(bp + (lr + 32) * 8) = b1;
}

// ---------------------------------------------------------------------------
// P1: each wave owns TWO query tiles (64 queries; B frags fixed in regs) so
// every A-tile ds_read_b128 feeds 2 MFMAs -> DS-pipe traffic halves vs r6
// (DS was the dominant pipe: ~10.2us wall). Streams a 64-tile ref segment
// through double-buffered LDS (4 chunks x 16KB, same barrier skeleton as r6).
// Min over the 16 in-lane rows is row-mapping-agnostic; C col = lane&31
// (HW-verified m74/m101); finish with shfl_xor(32).
// ---------------------------------------------------------------------------
__global__ __launch_bounds__(BLK) void chamfer_mfma(
    const short* __restrict__ apack, const short* __restrict__ bpack,
    float* __restrict__ partial)
{
    __shared__ __align__(16) short lds[2][8192];   // 2 x 16 KB (16 tiles each)
    const int bd  = blockIdx.z;     // 0..7
    const int seg = blockIdx.y;     // 0..3
    const int qb  = blockIdx.x;     // 0..31
    const int b = bd >> 1, dir = bd & 1;
    const short* ab = apack + (size_t)((dir ^ 1) * 4 + b) * (NPTS * 16)
                            + (size_t)seg * 64 * 512;    // this seg's 64 tiles
    const short* bb = bpack + (size_t)(dir * 4 + b) * (NPTS * 16);
    const int tid = threadIdx.x, wid = tid >> 6, lane = tid & 63;

    const int qt0 = qb * 8 + wid * 2;               // query tiles qt0, qt0+1
    const short8v bf0 = *(const short8v*)(bb + (size_t)qt0 * 512 + lane * 8);
    const short8v bf1 = *(const short8v*)(bb + (size_t)(qt0 + 1) * 512 + lane * 8);

    float mn0 = 3.4e38f, mn1 = 3.4e38f;
    short8v st[4];
#define LOADREGS(c) { const short* s_ = ab + (size_t)(c) * 8192;               \
    _Pragma("unroll") for (int i_ = 0; i_ < 4; i_++)                           \
        st[i_] = *(const short8v*)(s_ + i_ * 2048 + tid * 8); }
#define WRITEBUF(bf) { _Pragma("unroll") for (int i_ = 0; i_ < 4; i_++)        \
        *(short8v*)(&lds[bf][i_ * 2048 + tid * 8]) = st[i_]; }

    LOADREGS(0); WRITEBUF(0); LOADREGS(1);
    __syncthreads();
    for (int c = 0; c < 4; c++) {
        if (c + 1 < 4) WRITEBUF((c + 1) & 1);
        if (c + 2 < 4) LOADREGS(c + 2);
        const short* lbase = &lds[c & 1][lane * 8];
#pragma unroll
        for (int t = 0; t < 16; t++) {
            const short8v a = *(const short8v*)(lbase + t * 512);
            f32x16 d0 = __builtin_amdgcn_mfma_f32_32x32x16_bf16(
                a, bf0, (f32x16)(0.f), 0, 0, 0);
            {
                const float g0 = min3f(d0[0],  d0[1],  d0[2]);
                const float g1 = min3f(d0[3],  d0[4],  d0[5]);
                const float g2 = min3f(d0[6],  d0[7],  d0[8]);
                const float g3 = min3f(d0[9],  d0[10], d0[11]);
                const float g4 = min3f(d0[12], d0[13], d0[14]);
                mn0 = min3f(mn0, g0, g1);
                mn0 = min3f(mn0, g2, g3);
                mn0 = min3f(mn0, g4, d0[15]);
            }
            f32x16 d1 = __builtin_amdgcn_mfma_f32_32x32x16_bf16(
                a, bf1, (f32x16)(0.f), 0, 0, 0);
            {
                const float g0 = min3f(d1[0],  d1[1],  d1[2]);
                const float g1 = min3f(d1[3],  d1[4],  d1[5]);
                const float g2 = min3f(d1[6],  d1[7],  d1[8]);
                const float g3 = min3f(d1[9],  d1[10], d1[11]);
                const float g4 = min3f(d1[12], d1[13], d1[14]);
                mn1 = min3f(mn1, g0, g1);
                mn1 = min3f(mn1, g2, g3);
                mn1 = min3f(mn1, g4, d1[15]);
            }
        }
        __syncthreads();
    }
    mn0 = fminf(mn0, __shfl_xor(mn0, 32, 64));
    mn1 = fminf(mn1, __shfl_xor(mn1, 32, 64));
    if (lane < 32) {
        const size_t sb = ((size_t)bd * MSEG + seg) * NPTS;
        partial[sb + qt0 * 32 + lane]       = mn0;
        partial[sb + (qt0 + 1) * 32 + lane] = mn1;
    }
}

// ---------------------------------------------------------------------------
// P2: combine MSEG segment mins, add |q|^2 (exact fp32), clamp, sqrt, mean.
// ---------------------------------------------------------------------------
__global__ __launch_bounds__(BLK) void chamfer_reduce(
    const float* __restrict__ tmpl, const float* __restrict__ src,
    const float* __restrict__ partial, float* __restrict__ out)
{
    const int t  = blockIdx.x * BLK + threadIdx.x;  // 0 .. 8*NPTS-1
    const int bd = t >> 13;
    const int qi = t & (NPTS - 1);
    const int b  = bd >> 1;
    const int dir = bd & 1;
    const float* qp = (dir ? src : tmpl) + (size_t)b * NPTS * 3;
    const float qx = qp[3 * qi + 0];
    const float qy = qp[3 * qi + 1];
    const float qz = qp[3 * qi + 2];
    const float sq = qx * qx + qy * qy + qz * qz;

    float m = 3.4e38f;
#pragma unroll
    for (int s = 0; s < MSEG; s++)
        m = fminf(m, partial[((size_t)bd * MSEG + s) * NPTS + qi]);
    float v = sqrtf(fmaxf(sq + m, 0.f));

#pragma unroll
    for (int off = 32; off > 0; off >>= 1)
        v += __shfl_down(v, off, 64);

    __shared__ float wsum[BLK / 64];
    const int lane = threadIdx.x & 63;
    const int wid  = threadIdx.x >> 6;
    if (lane == 0) wsum[wid] = v;
    __syncthreads();
    if (threadIdx.x == 0) {
        float s = 0.f;
#pragma unroll
        for (int w = 0; w < BLK / 64; w++) s += wsum[w];
        atomicAdd(out, s * (1.0f / 65536.0f));
    }
}

extern "C" void kernel_launch(void* const* d_in, const int* in_sizes, int n_in,
                              void* d_out, int out_size, void* d_ws, size_t ws_size,
                              hipStream_t stream) {
    const float* tmpl = (const float*)d_in[0];
    const float* src  = (const float*)d_in[1];
    float* out = (float*)d_out;

    // ws layout: apack 2 MB | bpack 2 MB | partial 1 MB  (needs 5 MB)
    short* apack   = (short*)d_ws;
    short* bpack   = apack + (size_t)8 * NPTS * 16;
    float* partial = (float*)(bpack + (size_t)8 * NPTS * 16);

    chamfer_pack<<<(2 * NB * NPTS) / BLK, BLK, 0, stream>>>(tmpl, src, apack, bpack, out);

    dim3 g1(32, MSEG, 2 * NB);   // 32 x 4 x 8 = 1024 blocks (4/CU)
    chamfer_mfma<<<g1, BLK, 0, stream>>>(apack, bpack, partial);

    chamfer_reduce<<<(2 * NB * NPTS) / BLK, BLK, 0, stream>>>(tmpl, src, partial, out);
}

// Round 8
// 88.571 us; speedup vs baseline: 5.3500x; 1.0097x over previous
//
#include <hip/hip_runtime.h>
#include <math.h>

#define NPTS 8192
#define NB 4
#define BLK 256
#define MSEG 8          // ref segments per (b,dir); seg = 32 tiles = 1024 refs
#define QPW 4           // query tiles per wave (128 queries; 4 B-frags in regs)

typedef __attribute__((ext_vector_type(8))) short  short8v;  // 4 VGPRs = 8 bf16
typedef __attribute__((ext_vector_type(16))) float f32x16;   // MFMA 32x32 acc

__device__ __forceinline__ float min3f(float a, float b, float c) {
    float d;
    asm("v_min3_f32 %0, %1, %2, %3" : "=v"(d) : "v"(a), "v"(b), "v"(c));
    return d;
}
// RNE float->bf16 (no NaN inputs here)
__device__ __forceinline__ unsigned short f2bf(float f) {
    unsigned u = __float_as_uint(f);
    return (unsigned short)((u + 0x7FFFu + ((u >> 16) & 1u)) >> 16);
}
__device__ __forceinline__ float bf2f(unsigned short h) {
    return __uint_as_float(((unsigned)h) << 16);
}

// ---------------------------------------------------------------------------
// P0: pack the A (ref) side only into MFMA fragment order. B frags are now
// built in-register inside chamfer_mfma (bitwise-identical split code), so
// bpack is gone. K-slot pairing (A = refs, B = queries, m = -2q):
//  k0-2: rh_c * mh_c | k3-5: rl_c * mh_c | k6-8: rh_c * ml_c
//  k9:   w_h  * 1    | k10:  w_l  * 1    | k11-15: 0
// acc = (-2 q . r) + |r|^2. Lane l holds point (tile*32 + (l&31)),
// k-slots 8*(l>>5)..+7 as one contiguous short8v -> tile = 1024 B.
// Also zeroes out[0] (stream-ordered ahead of chamfer_reduce's atomicAdd).
// ---------------------------------------------------------------------------
__global__ __launch_bounds__(BLK) void chamfer_pack(
    const float* __restrict__ tmpl, const float* __restrict__ src,
    short* __restrict__ apack, float* __restrict__ out)
{
    if (blockIdx.x == 0 && threadIdx.x == 0) out[0] = 0.f;

    const int t   = blockIdx.x * BLK + threadIdx.x;   // 0..65535
    const int arr = t >> 15;
    const int b   = (t >> 13) & 3;
    const int i   = t & (NPTS - 1);
    const float* p = (arr ? src : tmpl) + ((size_t)b * NPTS + i) * 3;
    const float x = p[0], y = p[1], z = p[2];

    const unsigned short xh = f2bf(x), yh = f2bf(y), zh = f2bf(z);
    const unsigned short xl = f2bf(x - bf2f(xh));
    const unsigned short yl = f2bf(y - bf2f(yh));
    const unsigned short zl = f2bf(z - bf2f(zh));
    const float w = fmaf(x, x, fmaf(y, y, z * z));
    const unsigned short wh = f2bf(w);
    const unsigned short wl = f2bf(w - bf2f(wh));

    const size_t base = (size_t)(arr * 4 + b) * (NPTS * 16);  // shorts
    const int    tl   = i >> 5, lr = i & 31;
    short* ap = apack + base + (size_t)tl * 512;

    const short8v a0 = {(short)xh, (short)yh, (short)zh, (short)xl,
                        (short)yl, (short)zl, (short)xh, (short)yh};
    const short8v a1 = {(short)zh, (short)wh, (short)wl, 0, 0, 0, 0, 0};
    *(short8v*)(ap + lr * 8)        = a0;
    *(short8v*)(ap + (lr + 32) * 8) = a1;
}

// ---------------------------------------------------------------------------
// P1: each wave owns FOUR query tiles (128 queries; 4 B frags = 16 VGPRs,
// built in-register from raw floats) so every A-tile ds_read_b128 feeds
// 4 MFMAs. DS traffic: 131k wave-reads (~2.6us wall; was 5.1 r7, 10.2 r6).
// Streams a 32-tile ref segment through double-buffered LDS (2 x 16KB).
// Min over the 16 in-lane rows is row-mapping-agnostic; C col = lane&31
// (HW-verified m74/m101); finish with shfl_xor(32).
// ---------------------------------------------------------------------------
__global__ __launch_bounds__(BLK) void chamfer_mfma(
    const short* __restrict__ apack,
    const float* __restrict__ tmpl, const float* __restrict__ src,
    float* __restrict__ partial)
{
    __shared__ __align__(16) short lds[2][8192];   // 2 x 16 KB (16 tiles each)
    const int bd  = blockIdx.z;     // 0..7
    const int seg = blockIdx.y;     // 0..MSEG-1
    const int qb  = blockIdx.x;     // 0..15
    const int b = bd >> 1, dir = bd & 1;
    const short* ab = apack + (size_t)((dir ^ 1) * 4 + b) * (NPTS * 16)
                            + (size_t)seg * 32 * 512;    // this seg's 32 tiles
    const float* qp = (dir ? src : tmpl) + (size_t)b * NPTS * 3;
    const int tid = threadIdx.x, wid = tid >> 6, lane = tid & 63;

    // build 4 B-fragments in registers (identical split math to pack)
    const int qt0 = qb * 16 + wid * QPW;            // first of 4 query tiles
    short8v bf[QPW];
#pragma unroll
    for (int p = 0; p < QPW; p++) {
        const int qid = (qt0 + p) * 32 + (lane & 31);
        const float x = qp[3 * qid], y = qp[3 * qid + 1], z = qp[3 * qid + 2];
        const float mx = -2.f * x, my = -2.f * y, mz = -2.f * z;
        const unsigned short mxh = f2bf(mx), myh = f2bf(my), mzh = f2bf(mz);
        const unsigned short mxl = f2bf(mx - bf2f(mxh));
        const unsigned short myl = f2bf(my - bf2f(myh));
        const unsigned short mzl = f2bf(mz - bf2f(mzh));
        const unsigned short ONE = 0x3F80;  // bf16 1.0
        const short8v b0 = {(short)mxh, (short)myh, (short)mzh, (short)mxh,
                            (short)myh, (short)mzh, (short)mxl, (short)myl};
        const short8v b1 = {(short)mzl, (short)ONE, (short)ONE, 0, 0, 0, 0, 0};
        bf[p] = (lane < 32) ? b0 : b1;
    }

    float mn[QPW];
#pragma unroll
    for (int p = 0; p < QPW; p++) mn[p] = 3.4e38f;

    short8v st[4];
#define LOADREGS(c) { const short* s_ = ab + (size_t)(c) * 8192;               \
    _Pragma("unroll") for (int i_ = 0; i_ < 4; i_++)                           \
        st[i_] = *(const short8v*)(s_ + i_ * 2048 + tid * 8); }
#define WRITEBUF(bf_) { _Pragma("unroll") for (int i_ = 0; i_ < 4; i_++)       \
        *(short8v*)(&lds[bf_][i_ * 2048 + tid * 8]) = st[i_]; }

    LOADREGS(0); WRITEBUF(0); LOADREGS(1);
    __syncthreads();
    for (int c = 0; c < 2; c++) {
        if (c == 0) WRITEBUF(1);
        const short* lbase = &lds[c][lane * 8];
#pragma unroll
        for (int t = 0; t < 16; t++) {
            const short8v a = *(const short8v*)(lbase + t * 512);
#pragma unroll
            for (int p = 0; p < QPW; p++) {
                f32x16 d = __builtin_amdgcn_mfma_f32_32x32x16_bf16(
                    a, bf[p], (f32x16)(0.f), 0, 0, 0);
                const float g0 = min3f(d[0],  d[1],  d[2]);
                const float g1 = min3f(d[3],  d[4],  d[5]);
                const float g2 = min3f(d[6],  d[7],  d[8]);
                const float g3 = min3f(d[9],  d[10], d[11]);
                const float g4 = min3f(d[12], d[13], d[14]);
                mn[p] = min3f(mn[p], g0, g1);
                mn[p] = min3f(mn[p], g2, g3);
                mn[p] = min3f(mn[p], g4, d[15]);
            }
        }
        if (c == 0) __syncthreads();
    }

    const size_t sb = ((size_t)bd * MSEG + seg) * NPTS;
#pragma unroll
    for (int p = 0; p < QPW; p++) {
        mn[p] = fminf(mn[p], __shfl_xor(mn[p], 32, 64));
        if (lane < 32)
            partial[sb + (size_t)(qt0 + p) * 32 + lane] = mn[p];
    }
}

// ---------------------------------------------------------------------------
// P2: combine MSEG segment mins, add |q|^2 (exact fp32), clamp, sqrt, mean.
// ---------------------------------------------------------------------------
__global__ __launch_bounds__(BLK) void chamfer_reduce(
    const float* __restrict__ tmpl, const float* __restrict__ src,
    const float* __restrict__ partial, float* __restrict__ out)
{
    const int t  = blockIdx.x * BLK + threadIdx.x;  // 0 .. 8*NPTS-1
    const int bd = t >> 13;
    const int qi = t & (NPTS - 1);
    const int b  = bd >> 1;
    const int dir = bd & 1;
    const float* qp = (dir ? src : tmpl) + (size_t)b * NPTS * 3;
    const float qx = qp[3 * qi + 0];
    const float qy = qp[3 * qi + 1];
    const float qz = qp[3 * qi + 2];
    const float sq = qx * qx + qy * qy + qz * qz;

    float m = 3.4e38f;
#pragma unroll
    for (int s = 0; s < MSEG; s++)
        m = fminf(m, partial[((size_t)bd * MSEG + s) * NPTS + qi]);
    float v = sqrtf(fmaxf(sq + m, 0.f));

#pragma unroll
    for (int off = 32; off > 0; off >>= 1)
        v += __shfl_down(v, off, 64);

    __shared__ float wsum[BLK / 64];
    const int lane = threadIdx.x & 63;
    const int wid  = threadIdx.x >> 6;
    if (lane == 0) wsum[wid] = v;
    __syncthreads();
    if (threadIdx.x == 0) {
        float s = 0.f;
#pragma unroll
        for (int w = 0; w < BLK / 64; w++) s += wsum[w];
        atomicAdd(out, s * (1.0f / 65536.0f));
    }
}

extern "C" void kernel_launch(void* const* d_in, const int* in_sizes, int n_in,
                              void* d_out, int out_size, void* d_ws, size_t ws_size,
                              hipStream_t stream) {
    const float* tmpl = (const float*)d_in[0];
    const float* src  = (const float*)d_in[1];
    float* out = (float*)d_out;

    // ws layout: apack 2 MB | partial 2 MB  (needs 4 MB)
    short* apack   = (short*)d_ws;
    float* partial = (float*)(apack + (size_t)8 * NPTS * 16);

    chamfer_pack<<<(2 * NB * NPTS) / BLK, BLK, 0, stream>>>(tmpl, src, apack, out);

    dim3 g1(16, MSEG, 2 * NB);   // 16 x 8 x 8 = 1024 blocks (4/CU)
    chamfer_mfma<<<g1, BLK, 0, stream>>>(apack, tmpl, src, partial);

    chamfer_reduce<<<(2 * NB * NPTS) / BLK, BLK, 0, stream>>>(tmpl, src, partial, out);
}

// Round 9
// 84.052 us; speedup vs baseline: 5.6377x; 1.0538x over previous
//
#include <hip/hip_runtime.h>
#include <math.h>

#define NPTS 8192
#define NB 4
#define BLK 256
#define MSEG 8          // ref segments per (b,dir); seg = 32 tiles = 1024 refs
#define QPW 4           // query tiles per wave (128 queries; 4 B-frags in regs)

typedef __attribute__((ext_vector_type(8))) short  short8v;  // 4 VGPRs = 8 bf16
typedef __attribute__((ext_vector_type(16))) float f32x16;   // MFMA 32x32 acc

__device__ __forceinline__ float min3f(float a, float b, float c) {
    float d;
    asm("v_min3_f32 %0, %1, %2, %3" : "=v"(d) : "v"(a), "v"(b), "v"(c));
    return d;
}
// RNE float->bf16 (no NaN inputs here)
__device__ __forceinline__ unsigned short f2bf(float f) {
    unsigned u = __float_as_uint(f);
    return (unsigned short)((u + 0x7FFFu + ((u >> 16) & 1u)) >> 16);
}
__device__ __forceinline__ float bf2f(unsigned short h) {
    return __uint_as_float(((unsigned)h) << 16);
}

// ---------------------------------------------------------------------------
// P1 (merged pack+mfma): the block's 1024-ref segment is read RAW from
// global (12 KB, L2-resident) and its A-fragments are built directly in
// LDS (32 KB, whole segment resident -> ONE barrier, no double-buffering,
// no apack array, no pack dispatch).
// K-slot pairing (A = refs, B = queries, m = -2q):
//  k0-2: rh_c * mh_c | k3-5: rl_c * mh_c | k6-8: rh_c * ml_c
//  k9:   w_h  * 1    | k10:  w_l  * 1    | k11-15: 0
// acc = (-2 q . r) + |r|^2 (|q|^2 added in reduce; min commutes).
// Per A-tile: lane l holds point (tile*32 + (l&31)), k-slots 8*(l>>5)..+7
// as one contiguous short8v. Each wave owns FOUR query tiles (B-frags in
// regs, built from raw floats with bitwise-identical split math) so every
// ds_read_b128 feeds 4 MFMAs. Min over the 16 in-lane rows is
// row-mapping-agnostic; C col = lane&31 (HW-verified m74/m101); finish
// with shfl_xor(32). Also zeroes out[0] (stream-ordered before reduce).
// ---------------------------------------------------------------------------
__global__ __launch_bounds__(BLK) void chamfer_main(
    const float* __restrict__ tmpl, const float* __restrict__ src,
    float* __restrict__ partial, float* __restrict__ out)
{
    __shared__ __align__(16) short lds[32 * 512];   // 32 KB: 32 A-tiles
    const int bd  = blockIdx.z;     // 0..7
    const int seg = blockIdx.y;     // 0..MSEG-1
    const int qb  = blockIdx.x;     // 0..15
    const int b = bd >> 1, dir = bd & 1;
    const float* qp = (dir ? src : tmpl) + (size_t)b * NPTS * 3;
    const float* rp = (dir ? tmpl : src) + (size_t)b * NPTS * 3;
    const int tid = threadIdx.x, wid = tid >> 6, lane = tid & 63;

    if ((blockIdx.x | blockIdx.y | blockIdx.z | tid) == 0) out[0] = 0.f;

    // ---- build this segment's A-fragments directly in LDS ----
    const int rbase = seg * 1024;
#pragma unroll
    for (int rr = 0; rr < 4; rr++) {
        const int i = rr * BLK + tid;               // ref idx within segment
        const float* p = rp + (size_t)(rbase + i) * 3;
        const float x = p[0], y = p[1], z = p[2];
        const unsigned short xh = f2bf(x), yh = f2bf(y), zh = f2bf(z);
        const unsigned short xl = f2bf(x - bf2f(xh));
        const unsigned short yl = f2bf(y - bf2f(yh));
        const unsigned short zl = f2bf(z - bf2f(zh));
        const float w = fmaf(x, x, fmaf(y, y, z * z));
        const unsigned short wh = f2bf(w);
        const unsigned short wl = f2bf(w - bf2f(wh));
        const short8v a0 = {(short)xh, (short)yh, (short)zh, (short)xl,
                            (short)yl, (short)zl, (short)xh, (short)yh};
        const short8v a1 = {(short)zh, (short)wh, (short)wl, 0, 0, 0, 0, 0};
        short* ap = lds + (i >> 5) * 512;
        *(short8v*)(ap + (i & 31) * 8)        = a0;   // lane-contiguous 16B
        *(short8v*)(ap + ((i & 31) + 32) * 8) = a1;   // -> conflict-free
    }

    // ---- build 4 B-fragments in registers (identical split math) ----
    const int qt0 = qb * 16 + wid * QPW;            // first of 4 query tiles
    short8v bf[QPW];
#pragma unroll
    for (int p = 0; p < QPW; p++) {
        const int qid = (qt0 + p) * 32 + (lane & 31);
        const float x = qp[3 * qid], y = qp[3 * qid + 1], z = qp[3 * qid + 2];
        const float mx = -2.f * x, my = -2.f * y, mz = -2.f * z;
        const unsigned short mxh = f2bf(mx), myh = f2bf(my), mzh = f2bf(mz);
        const unsigned short mxl = f2bf(mx - bf2f(mxh));
        const unsigned short myl = f2bf(my - bf2f(myh));
        const unsigned short mzl = f2bf(mz - bf2f(mzh));
        const unsigned short ONE = 0x3F80;  // bf16 1.0
        const short8v b0 = {(short)mxh, (short)myh, (short)mzh, (short)mxh,
                            (short)myh, (short)mzh, (short)mxl, (short)myl};
        const short8v b1 = {(short)mzl, (short)ONE, (short)ONE, 0, 0, 0, 0, 0};
        bf[p] = (lane < 32) ? b0 : b1;
    }

    float mn[QPW];
#pragma unroll
    for (int p = 0; p < QPW; p++) mn[p] = 3.4e38f;

    __syncthreads();   // the kernel's only barrier

    const short* lbase = lds + lane * 8;
#pragma unroll 4
    for (int t = 0; t < 32; t++) {
        const short8v a = *(const short8v*)(lbase + t * 512);
#pragma unroll
        for (int p = 0; p < QPW; p++) {
            f32x16 d = __builtin_amdgcn_mfma_f32_32x32x16_bf16(
                a, bf[p], (f32x16)(0.f), 0, 0, 0);
            const float g0 = min3f(d[0],  d[1],  d[2]);
            const float g1 = min3f(d[3],  d[4],  d[5]);
            const float g2 = min3f(d[6],  d[7],  d[8]);
            const float g3 = min3f(d[9],  d[10], d[11]);
            const float g4 = min3f(d[12], d[13], d[14]);
            mn[p] = min3f(mn[p], g0, g1);
            mn[p] = min3f(mn[p], g2, g3);
            mn[p] = min3f(mn[p], g4, d[15]);
        }
    }

    const size_t sb = ((size_t)bd * MSEG + seg) * NPTS;
#pragma unroll
    for (int p = 0; p < QPW; p++) {
        mn[p] = fminf(mn[p], __shfl_xor(mn[p], 32, 64));
        if (lane < 32)
            partial[sb + (size_t)(qt0 + p) * 32 + lane] = mn[p];
    }
}

// ---------------------------------------------------------------------------
// P2: combine MSEG segment mins, add |q|^2 (exact fp32), clamp, sqrt, mean.
// ---------------------------------------------------------------------------
__global__ __launch_bounds__(BLK) void chamfer_reduce(
    const float* __restrict__ tmpl, const float* __restrict__ src,
    const float* __restrict__ partial, float* __restrict__ out)
{
    const int t  = blockIdx.x * BLK + threadIdx.x;  // 0 .. 8*NPTS-1
    const int bd = t >> 13;
    const int qi = t & (NPTS - 1);
    const int b  = bd >> 1;
    const int dir = bd & 1;
    const float* qp = (dir ? src : tmpl) + (size_t)b * NPTS * 3;
    const float qx = qp[3 * qi + 0];
    const float qy = qp[3 * qi + 1];
    const float qz = qp[3 * qi + 2];
    const float sq = qx * qx + qy * qy + qz * qz;

    float m = 3.4e38f;
#pragma unroll
    for (int s = 0; s < MSEG; s++)
        m = fminf(m, partial[((size_t)bd * MSEG + s) * NPTS + qi]);
    float v = sqrtf(fmaxf(sq + m, 0.f));

#pragma unroll
    for (int off = 32; off > 0; off >>= 1)
        v += __shfl_down(v, off, 64);

    __shared__ float wsum[BLK / 64];
    const int lane = threadIdx.x & 63;
    const int wid  = threadIdx.x >> 6;
    if (lane == 0) wsum[wid] = v;
    __syncthreads();
    if (threadIdx.x == 0) {
        float s = 0.f;
#pragma unroll
        for (int w = 0; w < BLK / 64; w++) s += wsum[w];
        atomicAdd(out, s * (1.0f / 65536.0f));
    }
}

extern "C" void kernel_launch(void* const* d_in, const int* in_sizes, int n_in,
                              void* d_out, int out_size, void* d_ws, size_t ws_size,
                              hipStream_t stream) {
    const float* tmpl = (const float*)d_in[0];
    const float* src  = (const float*)d_in[1];
    float* out = (float*)d_out;

    float* partial = (float*)d_ws;   // 2 MB: 8 bd x MSEG x NPTS floats

    dim3 g1(16, MSEG, 2 * NB);   // 16 x 8 x 8 = 1024 blocks (4/CU)
    chamfer_main<<<g1, BLK, 0, stream>>>(tmpl, src, partial, out);

    chamfer_reduce<<<(2 * NB * NPTS) / BLK, BLK, 0, stream>>>(tmpl, src, partial, out);
}